// Round 2
// baseline (8632.536 us; speedup 1.0000x reference)
//
#include <hip/hip_runtime.h>
#include <stdint.h>

typedef unsigned short u16;
typedef unsigned int u32;
typedef __attribute__((ext_vector_type(8))) short bf16x8;
typedef __attribute__((ext_vector_type(4))) float f32x4;

#define DEV __device__ __forceinline__

#define NB 512   // batch
#define NT 64    // time
#define NE 1536  // embed
#define NH 512   // hid == deter
#define NS 32    // stoch

// ---- workspace layout (bytes) ----
static constexpr size_t OFF_EOBS   = 0;                                    // [T][B][512] f32
static constexpr size_t OFF_DETERF = OFF_EOBS + (size_t)NT*NB*512*4;       // (unused, kept for layout stability)
static constexpr size_t OFF_STOCHF = OFF_DETERF + (size_t)2*NB*512*4;      // (unused)
static constexpr size_t OFF_D0     = OFF_STOCHF + (size_t)NB*32*4;         // [512] f32
static constexpr size_t OFF_S0     = OFF_D0 + 512*4;                       // [32] f32 (pad 256)
static constexpr size_t OFF_XD     = OFF_S0 + 256;                         // (unused)
static constexpr size_t OFF_WINPT  = OFF_XD + (size_t)2*NB*1024*2;         // [512 cols][64 K] swizzled
static constexpr size_t OFF_WGRUT  = OFF_WINPT + (size_t)512*64*2;         // [1536][1024] swizzled
static constexpr size_t OFF_WIMGT  = OFF_WGRUT + (size_t)1536*1024*2;      // [512][512] swizzled
static constexpr size_t OFF_WOBSDT = OFF_WIMGT + (size_t)512*512*2;        // [512][512] swizzled
static constexpr size_t OFF_WOBSET = OFF_WOBSDT + (size_t)512*512*2;       // [512][1536] swizzled
static constexpr size_t OFF_WIMST  = OFF_WOBSET + (size_t)512*1536*2;      // [64][512] swizzled
static constexpr size_t OFF_WOSTT  = OFF_WIMST + (size_t)64*512*2;         // [64][512] swizzled
static constexpr size_t WS_NEED    = OFF_WOSTT + (size_t)64*512*2;

DEV u16 f2b(float f) {
  u32 u = __builtin_bit_cast(u32, f);
  u32 r = (u + 0x7FFFu + ((u >> 16) & 1u)) >> 16;
  return (u16)r;
}
DEV float b2f(u16 h) { u32 u = (u32)h << 16; return __builtin_bit_cast(float, u); }
DEV u32 pk2(float a, float b) { return (u32)f2b(a) | ((u32)f2b(b) << 16); }
DEV float sigf(float x) { return 1.f / (1.f + __expf(-x)); }
DEV float siluf(float x) { return x * sigf(x); }
DEV float softplusf(float x) { return (x > 20.f) ? x : log1pf(__expf(x)); }
DEV f32x4 mfma16(bf16x8 a, bf16x8 b, f32x4 c) {
  return __builtin_amdgcn_mfma_f32_16x16x32_bf16(a, b, c, 0, 0, 0);
}
// swizzled B-fragment layout: element offset of (colgrp, kk, lane) 8-elt group.
// logical: element i of group = W[kk*32 + (lane>>4)*8 + i][colgrp*16 + (lane&15)]
DEV size_t bswz(int colgrp, int kkmax, int kk, int lane) {
  return (((size_t)colgrp * kkmax + kk) * 64 + lane) * 8;
}

// ---------------- weight conversion: f32 -> bf16, MFMA-fragment-swizzled ----------------
__global__ __launch_bounds__(256) void k_convert(
    const float* __restrict__ W_inp, const float* __restrict__ W_gru,
    const float* __restrict__ W_img, const float* __restrict__ W_obs,
    const float* __restrict__ W_ims, const float* __restrict__ W_ostat,
    char* __restrict__ ws) {
  u16* winpT  = (u16*)(ws + OFF_WINPT);
  u16* wgruT  = (u16*)(ws + OFF_WGRUT);
  u16* wimgT  = (u16*)(ws + OFF_WIMGT);
  u16* wobsdT = (u16*)(ws + OFF_WOBSDT);
  u16* wobseT = (u16*)(ws + OFF_WOBSET);
  u16* wimsT  = (u16*)(ws + OFF_WIMST);
  u16* wostT  = (u16*)(ws + OFF_WOSTT);
  int o = blockIdx.x * 256 + threadIdx.x;
  // common decode pieces
  if (o < 32768) {  // winp: K=64(pad from 38), N=512, KK=2
    int i = o & 7, lane = (o >> 3) & 63, rem = o >> 9;
    int kk = rem & 1, cg = rem >> 1;
    int col = cg*16 + (lane & 15), k = kk*32 + (lane >> 4)*8 + i;
    winpT[o] = (k < 38) ? f2b(W_inp[k*512 + col]) : (u16)0;
    return;
  }
  o -= 32768;
  if (o < 1572864) {  // wgru: K=1024, N=1536, KK=32
    int i = o & 7, lane = (o >> 3) & 63, rem = o >> 9;
    int kk = rem & 31, cg = rem >> 5;
    int col = cg*16 + (lane & 15), k = kk*32 + (lane >> 4)*8 + i;
    wgruT[o] = f2b(W_gru[(size_t)k*1536 + col]);
    return;
  }
  o -= 1572864;
  if (o < 262144) {  // wimg: K=512, N=512, KK=16
    int i = o & 7, lane = (o >> 3) & 63, rem = o >> 9;
    int kk = rem & 15, cg = rem >> 4;
    int col = cg*16 + (lane & 15), k = kk*32 + (lane >> 4)*8 + i;
    wimgT[o] = f2b(W_img[k*512 + col]);
    return;
  }
  o -= 262144;
  if (o < 262144) {  // wobsd: K=512, N=512, KK=16
    int i = o & 7, lane = (o >> 3) & 63, rem = o >> 9;
    int kk = rem & 15, cg = rem >> 4;
    int col = cg*16 + (lane & 15), k = kk*32 + (lane >> 4)*8 + i;
    wobsdT[o] = f2b(W_obs[k*512 + col]);
    return;
  }
  o -= 262144;
  if (o < 786432) {  // wobse: K=1536, N=512, KK=48
    int i = o & 7, lane = (o >> 3) & 63, rem = o >> 9;
    int kk = rem % 48, cg = rem / 48;
    int col = cg*16 + (lane & 15), k = kk*32 + (lane >> 4)*8 + i;
    wobseT[o] = f2b(W_obs[(size_t)(512 + k)*512 + col]);
    return;
  }
  o -= 786432;
  if (o < 32768) {  // wims: K=512, N=64, KK=16
    int i = o & 7, lane = (o >> 3) & 63, rem = o >> 9;
    int kk = rem & 15, cg = rem >> 4;
    int col = cg*16 + (lane & 15), k = kk*32 + (lane >> 4)*8 + i;
    wimsT[o] = f2b(W_ims[k*64 + col]);
    return;
  }
  o -= 32768;
  {  // wost: K=512, N=64, KK=16
    int i = o & 7, lane = (o >> 3) & 63, rem = o >> 9;
    int kk = rem & 15, cg = rem >> 4;
    int col = cg*16 + (lane & 15), k = kk*32 + (lane >> 4)*8 + i;
    wostT[o] = f2b(W_ostat[k*64 + col]);
  }
}

// ---------------- initial state ----------------
__global__ __launch_bounds__(256) void k_init_a(
    const float* __restrict__ W_init, const float* __restrict__ W_img,
    const float* __restrict__ g_img, const float* __restrict__ b_img,
    const float* __restrict__ W_ims, const float* __restrict__ b_ims,
    char* __restrict__ ws) {
  __shared__ float DL[512];
  __shared__ float HL[512];
  __shared__ float RED[256];
  float* d0 = (float*)(ws + OFF_D0);
  float* s0 = (float*)(ws + OFF_S0);
  const int t = threadIdx.x;
  for (int j = t; j < 512; j += 256) { float v = tanhf(W_init[j]); DL[j] = v; d0[j] = v; }
  __syncthreads();
  float pre0 = 0.f, pre1 = 0.f;
  for (int k = 0; k < 512; ++k) {
    float dv = DL[k];
    pre0 += dv * W_img[k*512 + t];
    pre1 += dv * W_img[k*512 + t + 256];
  }
  RED[t] = pre0 + pre1;
  __syncthreads();
  for (int s = 128; s > 0; s >>= 1) { if (t < s) RED[t] += RED[t + s]; __syncthreads(); }
  float m = RED[0] * (1.f/512.f);
  __syncthreads();
  RED[t] = pre0*pre0 + pre1*pre1;
  __syncthreads();
  for (int s = 128; s > 0; s >>= 1) { if (t < s) RED[t] += RED[t + s]; __syncthreads(); }
  float var = RED[0] * (1.f/512.f) - m*m;
  float inv = rsqrtf(var + 1e-3f);
  HL[t]       = siluf((pre0 - m)*inv*g_img[t] + b_img[t]);
  HL[t + 256] = siluf((pre1 - m)*inv*g_img[t+256] + b_img[t+256]);
  __syncthreads();
  if (t < 32) {
    float s = 0.f;
    for (int k = 0; k < 512; ++k) s += HL[k] * W_ims[k*64 + t];
    s0[t] = s + b_ims[t];
  }
}

// ---------------- phase 1: E_obs[t][b][:] = embed[b][t][:] @ W_obs[512:,:] ----------------
// BM=32, BN=512 (full). Each wave: 32 rows x 128 private cols. embed read exactly once.
__global__ __launch_bounds__(256) void k_phase1(
    const float* __restrict__ embed, char* __restrict__ ws) {
  const u16* wobse = (const u16*)(ws + OFF_WOBSET);
  float* eobs = (float*)(ws + OFF_EOBS);
  __shared__ u16 AL[32 * 40];
  const int tid = threadIdx.x;
  const int mb = blockIdx.x;   // 0..1023
  const int w = tid >> 6, l = tid & 63, l15 = l & 15, lk = l >> 4;
  const f32x4 fz = {0.f, 0.f, 0.f, 0.f};
  f32x4 acc[2][8];
  for (int a = 0; a < 2; ++a) for (int f = 0; f < 8; ++f) acc[a][f] = fz;
  const int srow = tid >> 3, sk4 = (tid & 7) * 4;
  const float* abase = embed + (size_t)(mb*32 + srow)*1536 + sk4;
  u16* adst = AL + srow*40 + sk4;
  for (int kk = 0; kk < 48; ++kk) {
    __syncthreads();
    {
      float4 v = *(const float4*)(abase + kk*32);
      uint2 q; q.x = pk2(v.x, v.y); q.y = pk2(v.z, v.w);
      *(uint2*)adst = q;
    }
    __syncthreads();
    bf16x8 af0 = *(const bf16x8*)(AL + l15*40 + lk*8);
    bf16x8 af1 = *(const bf16x8*)(AL + (16 + l15)*40 + lk*8);
    for (int f = 0; f < 8; ++f) {
      bf16x8 bf = *(const bf16x8*)(wobse + bswz(w*8 + f, 48, kk, l));
      acc[0][f] = mfma16(af0, bf, acc[0][f]);
      acc[1][f] = mfma16(af1, bf, acc[1][f]);
    }
  }
  for (int ar = 0; ar < 2; ++ar)
    for (int f = 0; f < 8; ++f) {
      int col = w*128 + f*16 + l15;
      for (int r = 0; r < 4; ++r) {
        int row = mb*32 + ar*16 + lk*4 + r;  // row = b*64 + t
        int bb = row >> 6, tt = row & 63;
        eobs[((size_t)tt*512 + bb)*512 + col] = acc[ar][f][r];
      }
    }
}

// ---------------- fused scan: 32 blocks x 512 threads; block owns 16 batch rows, all 64 steps ----------------
__global__ __launch_bounds__(512) void k_step(
    const float* __restrict__ action, const float* __restrict__ reset,
    const float* __restrict__ g_inp, const float* __restrict__ b_inp,
    const float* __restrict__ g_obs, const float* __restrict__ b_obs,
    const float* __restrict__ b_ostat, const float* __restrict__ npost,
    float* __restrict__ out, char* __restrict__ ws) {
  const u16* WINP  = (const u16*)(ws + OFF_WINPT);
  const u16* WGRU  = (const u16*)(ws + OFF_WGRUT);
  const u16* WOBSD = (const u16*)(ws + OFF_WOBSDT);
  const u16* WOST  = (const u16*)(ws + OFF_WOSTT);
  const float* eobs = (const float*)(ws + OFF_EOBS);
  const float* d0 = (const float*)(ws + OFF_D0);
  const float* s0 = (const float*)(ws + OFF_S0);

  __shared__ u16 XD[16 * 1032];       // [row][ x(0..511) | deter(512..1023) ] bf16, pad stride
  __shared__ u16 HL[16 * 520];        // obs hidden bf16
  __shared__ u16 CIN[16 * 72];        // concat(stoch, action) bf16, K padded to 64
  __shared__ float LNB[8][16][2];     // LN partials per wave
  __shared__ float STL[16 * 64];      // ostat pre-activations
  __shared__ float D0L[512];
  __shared__ float S0L[32];
  __shared__ float STO[16 * 32];      // stoch carry f32
  __shared__ float RL[16];            // reset per row

  const int tid = threadIdx.x;
  const int w = tid >> 6, l = tid & 63, l15 = l & 15, lk = l >> 4;
  const int mb = blockIdx.x;          // 0..31
  const int brow0 = mb * 16;
  const f32x4 fz = {0.f, 0.f, 0.f, 0.f};

  if (tid < 512) D0L[tid] = d0[tid];
  if (tid < 32) S0L[tid] = s0[tid];
  __syncthreads();
  // deter carry in registers: df[n][r] = deter[row=lk*4+r][col=w*64+n*16+l15]
  float df[4][4];
  for (int n = 0; n < 4; ++n) {
    int j = w*64 + n*16 + l15;
    float v = D0L[j];
    for (int r = 0; r < 4; ++r) {
      df[n][r] = v;
      XD[(lk*4 + r)*1032 + 512 + j] = f2b(v);
    }
  }
  { int rr = tid >> 5, i2 = tid & 31; STO[rr*32 + i2] = S0L[i2]; }
  __syncthreads();

  for (int t = 0; t < NT; ++t) {
    // ---- phase 0: reset blend ----
    if (tid < 16) RL[tid] = reset[(size_t)(brow0 + tid)*NT + t];
    __syncthreads();
    {
      int rr = tid >> 5, i2 = tid & 31;
      float r = RL[rr];
      if (r != 0.f) STO[rr*32 + i2] = STO[rr*32 + i2]*(1.f - r) + S0L[i2]*r;
    }
    for (int n = 0; n < 4; ++n) {
      int j = w*64 + n*16 + l15;
      for (int r = 0; r < 4; ++r) {
        float rv = RL[lk*4 + r];
        if (rv != 0.f) {
          float v = df[n][r]*(1.f - rv) + D0L[j]*rv;
          df[n][r] = v;
          XD[(lk*4 + r)*1032 + 512 + j] = f2b(v);
        }
      }
    }
    __syncthreads();
    // ---- phase 1: input MLP x = silu(LN(concat(stoch,a)@W_inp)) ----
    if (tid < 256) {
      int rr = tid >> 4, ko = (tid & 15)*4;
      float r = RL[rr], onem = 1.f - r;
      float v[4];
      for (int i = 0; i < 4; ++i) {
        int k = ko + i;
        float x;
        if (k < 32)      x = STO[rr*32 + k];
        else if (k < 38) x = action[((size_t)(brow0 + rr)*NT + t)*6 + (k - 32)] * onem;
        else             x = 0.f;
        v[i] = x;
      }
      uint2 q; q.x = pk2(v[0], v[1]); q.y = pk2(v[2], v[3]);
      *(uint2*)(CIN + rr*72 + ko) = q;
    }
    __syncthreads();
    {
      f32x4 ai[4]; for (int f = 0; f < 4; ++f) ai[f] = fz;
      for (int kk = 0; kk < 2; ++kk) {
        bf16x8 af = *(const bf16x8*)(CIN + l15*72 + kk*32 + lk*8);
        for (int f = 0; f < 4; ++f) {
          bf16x8 bf = *(const bf16x8*)(WINP + bswz(w*4 + f, 2, kk, l));
          ai[f] = mfma16(af, bf, ai[f]);
        }
      }
      for (int r = 0; r < 4; ++r) {
        float s1 = 0.f, s2 = 0.f;
        for (int f = 0; f < 4; ++f) { float v = ai[f][r]; s1 += v; s2 += v*v; }
        for (int d = 1; d < 16; d <<= 1) { s1 += __shfl_xor(s1, d); s2 += __shfl_xor(s2, d); }
        if (l15 == 0) { LNB[w][lk*4 + r][0] = s1; LNB[w][lk*4 + r][1] = s2; }
      }
      __syncthreads();
      float mr[4], ir[4];
      for (int r = 0; r < 4; ++r) {
        int row = lk*4 + r;
        float S1 = 0.f, S2 = 0.f;
        for (int wv = 0; wv < 8; ++wv) { S1 += LNB[wv][row][0]; S2 += LNB[wv][row][1]; }
        float m = S1 * (1.f/512.f);
        float var = S2 * (1.f/512.f) - m*m;
        mr[r] = m; ir[r] = rsqrtf(var + 1e-3f);
      }
      for (int f = 0; f < 4; ++f) {
        int col = w*64 + f*16 + l15;
        float gg = g_inp[col], bb = b_inp[col];
        for (int r = 0; r < 4; ++r) {
          float v = siluf((ai[f][r] - mr[r]) * ir[r] * gg + bb);
          XD[(lk*4 + r)*1032 + col] = f2b(v);
        }
      }
    }
    __syncthreads();
    // ---- phase 2: GRU GEMM [16 x 1024] @ [1024 x 1536], wave owns gate-triplet cols ----
    {
      f32x4 ag[12]; for (int f = 0; f < 12; ++f) ag[f] = fz;
      for (int kk = 0; kk < 32; ++kk) {
        bf16x8 af = *(const bf16x8*)(XD + l15*1032 + kk*32 + lk*8);
        #pragma unroll
        for (int f = 0; f < 12; ++f) {
          int cg = (f >> 2)*32 + w*4 + (f & 3);
          bf16x8 bf = *(const bf16x8*)(WGRU + bswz(cg, 32, kk, l));
          ag[f] = mfma16(af, bf, ag[f]);
        }
      }
      __syncthreads();  // all waves done reading XD deter
      for (int r = 0; r < 4; ++r) {
        int row = lk*4 + r;
        size_t ob = ((size_t)(brow0 + row)*NT + t)*704;
        for (int n = 0; n < 4; ++n) {
          int j = w*64 + n*16 + l15;
          float dold = df[n][r];
          float rg = sigf(ag[n][r]);
          float ca = tanhf(rg * ag[4 + n][r]);
          float up = sigf(ag[8 + n][r] - 1.f);
          float dn = up*ca + (1.f - up)*dold;
          df[n][r] = dn;
          XD[row*1032 + 512 + j] = f2b(dn);
          out[ob + 192 + j] = dn;
        }
      }
    }
    __syncthreads();
    // ---- phase 3: posterior h = silu(LN(deter_n@W_obsd + E_obs)) ----
    {
      f32x4 ao[4]; for (int f = 0; f < 4; ++f) ao[f] = fz;
      for (int kk = 0; kk < 16; ++kk) {
        bf16x8 af = *(const bf16x8*)(XD + l15*1032 + 512 + kk*32 + lk*8);
        for (int f = 0; f < 4; ++f) {
          bf16x8 bf = *(const bf16x8*)(WOBSD + bswz(w*4 + f, 16, kk, l));
          ao[f] = mfma16(af, bf, ao[f]);
        }
      }
      for (int f = 0; f < 4; ++f) {
        int col = w*64 + f*16 + l15;
        for (int r = 0; r < 4; ++r)
          ao[f][r] += eobs[((size_t)t*512 + brow0 + lk*4 + r)*512 + col];
      }
      for (int r = 0; r < 4; ++r) {
        float s1 = 0.f, s2 = 0.f;
        for (int f = 0; f < 4; ++f) { float v = ao[f][r]; s1 += v; s2 += v*v; }
        for (int d = 1; d < 16; d <<= 1) { s1 += __shfl_xor(s1, d); s2 += __shfl_xor(s2, d); }
        if (l15 == 0) { LNB[w][lk*4 + r][0] = s1; LNB[w][lk*4 + r][1] = s2; }
      }
      __syncthreads();
      float mr[4], ir[4];
      for (int r = 0; r < 4; ++r) {
        int row = lk*4 + r;
        float S1 = 0.f, S2 = 0.f;
        for (int wv = 0; wv < 8; ++wv) { S1 += LNB[wv][row][0]; S2 += LNB[wv][row][1]; }
        float m = S1 * (1.f/512.f);
        float var = S2 * (1.f/512.f) - m*m;
        mr[r] = m; ir[r] = rsqrtf(var + 1e-3f);
      }
      for (int f = 0; f < 4; ++f) {
        int col = w*64 + f*16 + l15;
        float gg = g_obs[col], bb = b_obs[col];
        for (int r = 0; r < 4; ++r) {
          float v = siluf((ao[f][r] - mr[r]) * ir[r] * gg + bb);
          HL[(lk*4 + r)*520 + col] = f2b(v);
        }
      }
    }
    __syncthreads();
    // ---- phase 4: ostat = h @ W_ostat (waves 0..3, full K each, 16 private cols) ----
    if (w < 4) {
      f32x4 q = fz;
      for (int kk = 0; kk < 16; ++kk) {
        bf16x8 af = *(const bf16x8*)(HL + l15*520 + kk*32 + lk*8);
        bf16x8 bf = *(const bf16x8*)(WOST + bswz(w, 16, kk, l));
        q = mfma16(af, bf, q);
      }
      for (int r = 0; r < 4; ++r)
        STL[(lk*4 + r)*64 + w*16 + l15] = q[r];
    }
    __syncthreads();
    // ---- sample + write q outputs + update stoch ----
    {
      int row = tid >> 5, i2 = tid & 31;
      float sm = STL[row*64 + i2] + b_ostat[i2];
      float ss = STL[row*64 + 32 + i2] + b_ostat[32 + i2];
      float qs = softplusf(ss) + 0.1f;
      float ns = npost[((size_t)t*512 + brow0 + row)*32 + i2];
      float qst = sm + qs*ns;
      size_t ob = ((size_t)(brow0 + row)*NT + t)*704;
      out[ob + i2] = sm;
      out[ob + 32 + i2] = qs;
      out[ob + 64 + i2] = qst;
      STO[row*32 + i2] = qst;
    }
    __syncthreads();
  }
}

// ---------------- phase 3 (post): prior branch for all (b,t) ----------------
__global__ __launch_bounds__(256) void k_p3(
    const float* __restrict__ g_img, const float* __restrict__ b_img,
    const float* __restrict__ b_ims, const float* __restrict__ nprior,
    float* __restrict__ out, char* __restrict__ ws) {
  const u16* wimgT = (const u16*)(ws + OFF_WIMGT);
  const u16* wimsT = (const u16*)(ws + OFF_WIMST);
  __shared__ u16 AL[32 * 40];
  __shared__ u16 HL[32 * 520];
  __shared__ float LNB[4][32][2];
  __shared__ float STL[32 * 64];
  const int tid = threadIdx.x;
  const int mb = blockIdx.x;   // 0..1023
  const int w = tid >> 6, l = tid & 63, l15 = l & 15, lk = l >> 4;
  const f32x4 fz = {0.f,0.f,0.f,0.f};
  f32x4 acc[2][8];
  for (int rb = 0; rb < 2; ++rb) for (int f = 0; f < 8; ++f) acc[rb][f] = fz;
  const int srow = tid >> 3, sko = (tid & 7) * 4;
  const float* sbase = out + (size_t)(mb*32 + srow)*704 + 192 + sko;  // deter_n
  u16* sdst = AL + srow*40 + sko;
  for (int kk = 0; kk < 16; ++kk) {
    __syncthreads();
    {
      float4 v = *(const float4*)(sbase + kk*32);
      uint2 q; q.x = pk2(v.x, v.y); q.y = pk2(v.z, v.w);
      *(uint2*)sdst = q;
    }
    __syncthreads();
    bf16x8 af0 = *(const bf16x8*)(AL + l15*40 + lk*8);
    bf16x8 af1 = *(const bf16x8*)(AL + (16 + l15)*40 + lk*8);
    for (int f = 0; f < 8; ++f) {
      bf16x8 bf = *(const bf16x8*)(wimgT + bswz(w*8 + f, 16, kk, l));
      acc[0][f] = mfma16(af0, bf, acc[0][f]);
      acc[1][f] = mfma16(af1, bf, acc[1][f]);
    }
  }
  for (int rb = 0; rb < 2; ++rb) {
    for (int r = 0; r < 4; ++r) {
      float s1 = 0.f, s2 = 0.f;
      for (int f = 0; f < 8; ++f) { float v = acc[rb][f][r]; s1 += v; s2 += v*v; }
      for (int d = 1; d < 16; d <<= 1) { s1 += __shfl_xor(s1, d); s2 += __shfl_xor(s2, d); }
      if (l15 == 0) { LNB[w][rb*16 + lk*4 + r][0] = s1; LNB[w][rb*16 + lk*4 + r][1] = s2; }
    }
  }
  __syncthreads();
  for (int rb = 0; rb < 2; ++rb) {
    float mr[4], ir[4];
    for (int r = 0; r < 4; ++r) {
      int row = rb*16 + lk*4 + r;
      float S1 = LNB[0][row][0] + LNB[1][row][0] + LNB[2][row][0] + LNB[3][row][0];
      float S2 = LNB[0][row][1] + LNB[1][row][1] + LNB[2][row][1] + LNB[3][row][1];
      float m = S1 * (1.f/512.f);
      float var = S2 * (1.f/512.f) - m*m;
      mr[r] = m; ir[r] = rsqrtf(var + 1e-3f);
    }
    for (int f = 0; f < 8; ++f) {
      int col = w*128 + f*16 + l15;
      float gg = g_img[col], bb = b_img[col];
      for (int r = 0; r < 4; ++r) {
        float v = siluf((acc[rb][f][r] - mr[r]) * ir[r] * gg + bb);
        HL[(rb*16 + lk*4 + r)*520 + col] = f2b(v);
      }
    }
  }
  __syncthreads();
  f32x4 q0 = fz, q1 = fz;
  for (int kk = 0; kk < 16; ++kk) {
    bf16x8 bf = *(const bf16x8*)(wimsT + bswz(w, 16, kk, l));
    bf16x8 af0 = *(const bf16x8*)(HL + l15*520 + kk*32 + lk*8);
    bf16x8 af1 = *(const bf16x8*)(HL + (16 + l15)*520 + kk*32 + lk*8);
    q0 = mfma16(af0, bf, q0);
    q1 = mfma16(af1, bf, q1);
  }
  float bia = b_ims[w*16 + l15];
  for (int r = 0; r < 4; ++r) {
    STL[(lk*4 + r)*64 + w*16 + l15] = q0[r] + bia;
    STL[(16 + lk*4 + r)*64 + w*16 + l15] = q1[r] + bia;
  }
  __syncthreads();
  for (int it = tid; it < 1024; it += 256) {
    int row = it >> 5, i = it & 31;
    int grow = mb*32 + row;
    int bb = grow >> 6, tt = grow & 63;
    float pm = STL[row*64 + i];
    float ps = softplusf(STL[row*64 + 32 + i]) + 0.1f;
    float nr = nprior[((size_t)tt*512 + bb)*32 + i];
    float pst = pm + ps*nr;
    size_t ob = (size_t)grow*704;
    out[ob + 96 + i] = pm;
    out[ob + 128 + i] = ps;
    out[ob + 160 + i] = pst;
  }
}

extern "C" void kernel_launch(void* const* d_in, const int* in_sizes, int n_in,
                              void* d_out, int out_size, void* d_ws, size_t ws_size,
                              hipStream_t stream) {
  const float* embed   = (const float*)d_in[0];
  const float* action  = (const float*)d_in[1];
  const float* reset   = (const float*)d_in[2];
  const float* npost   = (const float*)d_in[3];
  const float* nprior  = (const float*)d_in[4];
  const float* W_inp   = (const float*)d_in[5];
  const float* g_inp   = (const float*)d_in[6];
  const float* b_inp   = (const float*)d_in[7];
  const float* W_gru   = (const float*)d_in[8];
  const float* W_img   = (const float*)d_in[9];
  const float* g_img   = (const float*)d_in[10];
  const float* b_img   = (const float*)d_in[11];
  const float* W_obs   = (const float*)d_in[12];
  const float* g_obs   = (const float*)d_in[13];
  const float* b_obs   = (const float*)d_in[14];
  const float* W_ims   = (const float*)d_in[15];
  const float* b_ims   = (const float*)d_in[16];
  const float* W_ostat = (const float*)d_in[17];
  const float* b_ostat = (const float*)d_in[18];
  const float* W_init  = (const float*)d_in[19];
  float* out = (float*)d_out;
  char* ws = (char*)d_ws;
  if (ws_size < WS_NEED) return;

  k_convert<<<11648, 256, 0, stream>>>(W_inp, W_gru, W_img, W_obs, W_ims, W_ostat, ws);
  k_init_a<<<1, 256, 0, stream>>>(W_init, W_img, g_img, b_img, W_ims, b_ims, ws);
  k_phase1<<<1024, 256, 0, stream>>>(embed, ws);
  k_step<<<32, 512, 0, stream>>>(action, reset, g_inp, b_inp, g_obs, b_obs,
                                 b_ostat, npost, out, ws);
  k_p3<<<1024, 256, 0, stream>>>(g_img, b_img, b_ims, nprior, out, ws);
}